// Round 4
// baseline (51.595 us; speedup 1.0000x reference)
//
#include <hip/hip_runtime.h>

#define NQ 12
#define NL 5
#define TPB 256

// ---------- compile-time address algebra (all GF(2)-linear) ----------
// suffix-XOR over 12 bits: bit k of result = XOR of input bits >= k
__host__ __device__ constexpr int sfx12(int x) {
    x ^= x >> 1; x ^= x >> 2; x ^= x >> 4; x ^= x >> 8;
    return x & 0xFFF;
}
// swizzled byte address of amplitude i:
//   g = i>>1; G = g ^ ((g>>3)&7) ^ ((g>>6)&7); addr = G<<4 | (i&1)<<3
// Linear in i's bits => addr(a^b) = addr(a)^addr(b).
__host__ __device__ constexpr int amp_addr(int i) {
    const int g = i >> 1;
    const int G = g ^ ((g >> 3) & 7) ^ ((g >> 6) & 7);
    return (G << 4) | ((i & 1) << 3);
}
// CNOT ring: new[i] = old[f(i)], f(j)=j^(j>>1)^((j&1)*0xC00).
// Inverse: f^-1(i) = sfx12(i) ^ (parity(i)<<11)  (verified: f(0x7FF)=0x800).
// m-part (amp bits 8..11) of the scatter destination address:
__host__ __device__ constexpr int scat_c(int m) {
    const int s = sfx12(m << 8);              // s&1 == parity(m)
    return amp_addr(s ^ ((s & 1) << 11));
}
// pass-2 read-address m-part
__host__ __device__ constexpr int p2_c(int m) { return amp_addr(m << 8); }

// ---------- DPP lane exchange (quad_perm) ----------
template <int CTRL>
__device__ __forceinline__ float dppx(float v) {
    return __int_as_float(__builtin_amdgcn_update_dpp(
        0, __float_as_int(v), CTRL, 0xF, 0xF, true));
}

// ---------- gate kernels ----------
__device__ __forceinline__ void gate_pair(float2 &a, float2 &c,
        const float2 u00, const float2 u01, const float2 u10, const float2 u11) {
    float2 n0, n1;
    n0.x = fmaf(u00.x, a.x, fmaf(-u00.y, a.y, fmaf(u01.x, c.x, -u01.y * c.y)));
    n0.y = fmaf(u00.x, a.y, fmaf( u00.y, a.x, fmaf(u01.x, c.y,  u01.y * c.x)));
    n1.x = fmaf(u10.x, a.x, fmaf(-u10.y, a.y, fmaf(u11.x, c.x, -u11.y * c.y)));
    n1.y = fmaf(u10.x, a.y, fmaf( u10.y, a.x, fmaf(u11.x, c.y,  u11.y * c.x)));
    a = n0; c = n1;
}

// gate on register-index bit K
template <int K>
__device__ __forceinline__ void apply_gate(float2 (&v)[16], const float2* __restrict__ Uq) {
    const float2 u00 = Uq[0], u01 = Uq[1], u10 = Uq[2], u11 = Uq[3];
#pragma unroll
    for (int h = 0; h < 8; ++h) {
        const int m0 = ((h >> K) << (K + 1)) | (h & ((1 << K) - 1));
        gate_pair(v[m0], v[m0 | (1 << K)], u00, u01, u10, u11);
    }
}

// gate on lane bit LBIT (amp bit carried by the lane index), partner via DPP.
// Lane with bit=0 holds 'a' (coeffs u00,u01); bit=1 holds 'c' (u11,u10).
template <int CTRL, int LBIT>
__device__ __forceinline__ void dpp_gate(float2 (&v)[16], const float2* __restrict__ Uq,
                                         const int lane) {
    const bool hi = (lane >> LBIT) & 1;
    const float2 u00 = Uq[0], u01 = Uq[1], u10 = Uq[2], u11 = Uq[3];
    const float2 co = hi ? u11 : u00;   // coeff * own
    const float2 cp = hi ? u10 : u01;   // coeff * partner
#pragma unroll
    for (int r = 0; r < 16; ++r) {
        const float ox = v[r].x, oy = v[r].y;
        const float px = dppx<CTRL>(ox);
        const float py = dppx<CTRL>(oy);
        v[r].x = fmaf(co.x, ox, fmaf(-co.y, oy, fmaf(cp.x, px, -cp.y * py)));
        v[r].y = fmaf(co.x, oy, fmaf( co.y, ox, fmaf(cp.x, py,  cp.y * px)));
    }
}

extern "C" __global__ void __launch_bounds__(TPB)
qnet_kernel(const float* __restrict__ x, const float* __restrict__ iw,
            const float* __restrict__ th, const float* __restrict__ ow,
            float* __restrict__ out) {
    __shared__ float2 st[4096];                      // 32 KB state, swizzled
    __shared__ __align__(16) float2 U[NL][NQ][4];    // gate matrices
    __shared__ float wz[4][4];
    char* stb = (char*)st;

    const int b = blockIdx.x;
    const int tid = threadIdx.x;
    const int Ln = tid & 63;     // lane
    const int w  = tid >> 6;     // wave

    // --- precompute all 60 gate matrices U = M(b,c) @ Rx(a) ---
    if (tid < NL * NQ) {
        const int l = tid / NQ, q = tid % NQ;
        const float xv = tanhf(x[b * NQ + q]);
        const float a = iw[l * NQ + q] * xv;
        const float bt = th[(l * NQ + q) * 2 + 0];
        const float ct = th[(l * NQ + q) * 2 + 1];
        float sa, ca; sincosf(0.5f * a, &sa, &ca);
        float sb, cb; sincosf(0.5f * bt, &sb, &cb);
        float sc, cc; sincosf(0.5f * ct, &sc, &cc);
        const float M00r = cc * cb, M00i = -sc * cb;
        const float M01r = -cc * sb, M01i = sc * sb;
        const float M10r = cc * sb, M10i = sc * sb;
        const float M11r = cc * cb, M11i = sc * cb;
        U[l][q][0] = make_float2(fmaf(M00r, ca,  sa * M01i), fmaf(M00i, ca, -sa * M01r));
        U[l][q][1] = make_float2(fmaf(ca, M01r,  sa * M00i), fmaf(ca, M01i, -sa * M00r));
        U[l][q][2] = make_float2(fmaf(M10r, ca,  sa * M11i), fmaf(M10i, ca, -sa * M11r));
        U[l][q][3] = make_float2(fmaf(ca, M11r,  sa * M10i), fmaf(ca, M11i, -sa * M10r));
    }

    // --- per-thread address bases (1 XOR w/ literal per LDS access in the loop) ---
    const int base1 = amp_addr(tid << 4);                             // pass1: ^ (c<<4)
    const int T2 = ((Ln & 3) << 6) | (w << 4) | (Ln >> 2);            // pass2 thread part
    const int base2 = amp_addr(T2);                                   // pass2: ^ p2_c(m)
    const int sT = sfx12(T2);
    const int baseS = amp_addr(sT ^ ((sT & 1) << 11));                // scatter: ^ scat_c(m)

    __syncthreads();   // U visible

    float2 v[16];
    for (int l = 0; l < NL; ++l) {
        // ---- pass 1: amp bits 0-5 = qubits 11..6 (4 reg gates + 2 DPP gates) ----
        if (l == 0) {
#pragma unroll
            for (int r = 0; r < 16; ++r) v[r] = make_float2(0.f, 0.f);
            if (tid == 0) v[0].x = 1.f;          // |0...0>
        } else {
#pragma unroll
            for (int c = 0; c < 8; ++c) {
                const float4 f = *(const float4*)(stb + (base1 ^ (c << 4)));
                v[2 * c]     = make_float2(f.x, f.y);
                v[2 * c + 1] = make_float2(f.z, f.w);
            }
        }
        apply_gate<0>(v, U[l][11]);
        apply_gate<1>(v, U[l][10]);
        apply_gate<2>(v, U[l][9]);
        apply_gate<3>(v, U[l][8]);
        dpp_gate<0xB1, 0>(v, U[l][7], Ln);       // amp bit 4 (lane^1)
        dpp_gate<0x4E, 1>(v, U[l][6], Ln);       // amp bit 5 (lane^2)
#pragma unroll
        for (int c = 0; c < 8; ++c)
            *(float4*)(stb + (base1 ^ (c << 4))) =
                make_float4(v[2 * c].x, v[2 * c].y, v[2 * c + 1].x, v[2 * c + 1].y);
        __syncthreads();

        // ---- pass 2: amp bits 6-11 = qubits 5..0 (2 DPP gates + 4 reg gates) ----
#pragma unroll
        for (int m = 0; m < 16; ++m)
            v[m] = *(const float2*)(stb + (base2 ^ p2_c(m)));
        dpp_gate<0xB1, 0>(v, U[l][5], Ln);       // amp bit 6 (lane^1)
        dpp_gate<0x4E, 1>(v, U[l][4], Ln);       // amp bit 7 (lane^2)
        apply_gate<0>(v, U[l][3]);
        apply_gate<1>(v, U[l][2]);
        apply_gate<2>(v, U[l][1]);
        apply_gate<3>(v, U[l][0]);
        __syncthreads();   // everyone's pass-2 reads done before scatter overwrites
        // CNOT-ring fused scatter: amp i -> address of f^-1(i)
#pragma unroll
        for (int m = 0; m < 16; ++m)
            *(float2*)(stb + (baseS ^ scat_c(m))) = v[m];
        __syncthreads();
    }

    // --- measurement: state canonical (perm already applied); own b128 chunks ---
    float ps = 0.f;
#pragma unroll
    for (int c = 0; c < 8; ++c) {
        const float4 f = *(const float4*)(stb + (base1 ^ (c << 4)));
        ps = fmaf(f.x, f.x, fmaf(f.y, f.y, fmaf(f.z, f.z, fmaf(f.w, f.w, ps))));
    }
    // Z on qubits 0..3 = amp bits 11..8 = tid bits 7..4 (constant per thread)
    float s0 = (tid & 128) ? -ps : ps;
    float s1 = (tid & 64) ? -ps : ps;
    float s2 = (tid & 32) ? -ps : ps;
    float s3 = (tid & 16) ? -ps : ps;
#pragma unroll
    for (int off = 32; off > 0; off >>= 1) {
        s0 += __shfl_xor(s0, off);
        s1 += __shfl_xor(s1, off);
        s2 += __shfl_xor(s2, off);
        s3 += __shfl_xor(s3, off);
    }
    if ((tid & 63) == 0) {
        wz[w][0] = s0; wz[w][1] = s1; wz[w][2] = s2; wz[w][3] = s3;
    }
    __syncthreads();
    if (tid < 4) {
        const float z = wz[0][tid] + wz[1][tid] + wz[2][tid] + wz[3][tid];
        out[b * 4 + tid] = ow[tid] * z;
    }
}

extern "C" void kernel_launch(void* const* d_in, const int* in_sizes, int n_in,
                              void* d_out, int out_size, void* d_ws, size_t ws_size,
                              hipStream_t stream) {
    const float* x  = (const float*)d_in[0];
    const float* iw = (const float*)d_in[1];
    const float* th = (const float*)d_in[2];
    const float* ow = (const float*)d_in[3];
    float* out = (float*)d_out;
    const int batch = in_sizes[0] / NQ;
    hipLaunchKernelGGL(qnet_kernel, dim3(batch), dim3(TPB), 0, stream,
                       x, iw, th, ow, out);
}

// Round 5
// 51.505 us; speedup vs baseline: 1.0018x; 1.0018x over previous
//
#include <hip/hip_runtime.h>

#define NQ 12
#define NL 5
#define TPB 256

// ---------- compile-time address algebra (GF(2)-linear, R3-verified) ----------
__host__ __device__ constexpr int sfx12_(int x) {
    x ^= x >> 1; x ^= x >> 2; x ^= x >> 4; x ^= x >> 8;
    return x & 0xFFF;
}
__host__ __device__ constexpr int par_(int x) {
    int y = x; y ^= y >> 8; y ^= y >> 4; y ^= y >> 2; y ^= y >> 1;
    return y & 1;
}
// amp i lives at byte (G<<4)|((i&1)<<3), G = g ^ ((g>>3)&7), g = i>>1.
__host__ __device__ constexpr int amp_addr(int i) {
    const int g = i >> 1;
    const int G = g ^ ((g >> 3) & 7);
    return (G << 4) | ((i & 1) << 3);
}
// CNOT ring: new[i] = old[f(i)], f(j)=j^(j>>1)^((j&1)*0xC00); f^-1(i)=sfx12(i)^(par(i)<<11).
__host__ __device__ constexpr int scat_c(int m) {          // scatter m-part address
    const int s = sfx12_(m << 8);
    return amp_addr(s ^ ((s & 1) << 11));
}
__host__ __device__ constexpr int bpat(int m) { return amp_addr(m << 4); }   // pass-B m-part
__host__ __device__ constexpr int meas_h(int m) {          // bits 11..8 of f^-1(m<<8)
    const int d = sfx12_(m << 8) ^ (par_(m) << 11);
    return (d >> 8) & 15;
}

// ---------- complex helpers ----------
__device__ __forceinline__ float2 cmul(float2 a, float2 b) {
    return make_float2(fmaf(a.x, b.x, -a.y * b.y), fmaf(a.x, b.y, a.y * b.x));
}
__device__ __forceinline__ void gate_pair(float2 &a, float2 &c,
        const float2 u00, const float2 u01, const float2 u10, const float2 u11) {
    float2 n0, n1;
    n0.x = fmaf(u00.x, a.x, fmaf(-u00.y, a.y, fmaf(u01.x, c.x, -u01.y * c.y)));
    n0.y = fmaf(u00.x, a.y, fmaf( u00.y, a.x, fmaf(u01.x, c.y,  u01.y * c.x)));
    n1.x = fmaf(u10.x, a.x, fmaf(-u10.y, a.y, fmaf(u11.x, c.x, -u11.y * c.y)));
    n1.y = fmaf(u10.x, a.y, fmaf( u10.y, a.x, fmaf(u11.x, c.y,  u11.y * c.x)));
    a = n0; c = n1;
}
template <int K>
__device__ __forceinline__ void apply_gate(float2 (&v)[16], const float2* __restrict__ Uq) {
    const float2 u00 = Uq[0], u01 = Uq[1], u10 = Uq[2], u11 = Uq[3];
#pragma unroll
    for (int h = 0; h < 8; ++h) {
        const int m0 = ((h >> K) << (K + 1)) | (h & ((1 << K) - 1));
        gate_pair(v[m0], v[m0 | (1 << K)], u00, u01, u10, u11);
    }
}

extern "C" __global__ void __launch_bounds__(TPB)
qnet_kernel(const float* __restrict__ x, const float* __restrict__ iw,
            const float* __restrict__ th, const float* __restrict__ ow,
            float* __restrict__ out) {
    __shared__ float2 st[4096];                      // 32 KB state, swizzled
    __shared__ __align__(16) float2 U[NL][NQ][4];    // gate matrices
    __shared__ float wz[4][4];
    char* stb = (char*)st;

    const int b = blockIdx.x;
    const int tid = threadIdx.x;
    const int w = tid >> 6;

    // --- precompute all 60 gate matrices U = M(b,c) @ Rx(a) ---
    if (tid < NL * NQ) {
        const int l = tid / NQ, q = tid % NQ;
        const float xv = tanhf(x[b * NQ + q]);
        const float a = iw[l * NQ + q] * xv;
        const float bt = th[(l * NQ + q) * 2 + 0];
        const float ct = th[(l * NQ + q) * 2 + 1];
        float sa, ca; sincosf(0.5f * a, &sa, &ca);
        float sb, cb; sincosf(0.5f * bt, &sb, &cb);
        float sc, cc; sincosf(0.5f * ct, &sc, &cc);
        const float M00r = cc * cb, M00i = -sc * cb;
        const float M01r = -cc * sb, M01i = sc * sb;
        const float M10r = cc * sb, M10i = sc * sb;
        const float M11r = cc * cb, M11i = sc * cb;
        U[l][q][0] = make_float2(fmaf(M00r, ca,  sa * M01i), fmaf(M00i, ca, -sa * M01r));
        U[l][q][1] = make_float2(fmaf(ca, M01r,  sa * M00i), fmaf(ca, M01i, -sa * M00r));
        U[l][q][2] = make_float2(fmaf(M10r, ca,  sa * M11i), fmaf(M10i, ca, -sa * M11r));
        U[l][q][3] = make_float2(fmaf(ca, M11r,  sa * M10i), fmaf(ca, M11i, -sa * M10r));
    }

    // --- per-thread address bases ---
    const int baseA = amp_addr(tid << 4);                              // ^ (c<<4)
    const int baseB = amp_addr(((tid >> 4) << 8) | (tid & 15));        // ^ bpat(m)
    const int baseC = amp_addr(tid);                                   // + (m<<11)
    const int pt = __popc(tid) & 1;
    const int baseS = amp_addr(sfx12_(tid) ^ (pt << 11));              // ^ scat_c(m)
    const int hT = pt << 3;                                            // f^-1 t-part hi nibble

    __syncthreads();   // U visible

    float2 v[16];
    for (int l = 0; l < NL; ++l) {
        // ---- pass A: amp bits 0-3 (qubits 11..8); wave-local region ----
        if (l == 0) {
            // |0..0>: closed-form column-0 products; only thread 0 nonzero
            float2 p[16];
            p[0] = make_float2(1.f, 0.f);
#pragma unroll
            for (int k = 0; k < 4; ++k) {
                const float2 u00 = U[0][11 - k][0], u10 = U[0][11 - k][2];
#pragma unroll
                for (int j = 0; j < (1 << k); ++j) {
                    p[j | (1 << k)] = cmul(p[j], u10);
                    p[j] = cmul(p[j], u00);
                }
            }
            const float msk = (tid == 0) ? 1.f : 0.f;
#pragma unroll
            for (int r = 0; r < 16; ++r) v[r] = make_float2(p[r].x * msk, p[r].y * msk);
        } else {
#pragma unroll
            for (int c = 0; c < 8; ++c) {
                const float4 f = *(const float4*)(stb + (baseA ^ (c << 4)));
                v[2 * c]     = make_float2(f.x, f.y);
                v[2 * c + 1] = make_float2(f.z, f.w);
            }
            apply_gate<0>(v, U[l][11]);
            apply_gate<1>(v, U[l][10]);
            apply_gate<2>(v, U[l][9]);
            apply_gate<3>(v, U[l][8]);
        }
#pragma unroll
        for (int c = 0; c < 8; ++c)
            *(float4*)(stb + (baseA ^ (c << 4))) =
                make_float4(v[2 * c].x, v[2 * c].y, v[2 * c + 1].x, v[2 * c + 1].y);
        // A and B touch only this wave's 8KB slice: wave-level LDS ordering suffices.
        asm volatile("s_waitcnt lgkmcnt(0)" ::: "memory");

        // ---- pass B: amp bits 4-7 (qubits 7..4); wave-local region ----
        if (l == 0) {
            float2 q[16];
            q[0] = make_float2(1.f, 0.f);
#pragma unroll
            for (int k = 0; k < 4; ++k) {
                const float2 u00 = U[0][7 - k][0], u10 = U[0][7 - k][2];
#pragma unroll
                for (int j = 0; j < (1 << k); ++j) {
                    q[j | (1 << k)] = cmul(q[j], u10);
                    q[j] = cmul(q[j], u00);
                }
            }
            // amps 0..15 live at bytes (t&15)<<3; nonzero only for threads 0..15
            const float2 w0 = *(const float2*)(stb + ((tid & 15) << 3));
            const float msk = (tid < 16) ? 1.f : 0.f;
            const float2 ww = make_float2(w0.x * msk, w0.y * msk);
#pragma unroll
            for (int m = 0; m < 16; ++m) v[m] = cmul(q[m], ww);
        } else {
#pragma unroll
            for (int m = 0; m < 16; ++m)
                v[m] = *(const float2*)(stb + (baseB ^ bpat(m)));
            apply_gate<0>(v, U[l][7]);
            apply_gate<1>(v, U[l][6]);
            apply_gate<2>(v, U[l][5]);
            apply_gate<3>(v, U[l][4]);
        }
#pragma unroll
        for (int m = 0; m < 16; ++m)
            *(float2*)(stb + (baseB ^ bpat(m))) = v[m];
        __syncthreads();   // bar1: pass C reads cross-wave

        // ---- pass C: amp bits 8-11 (qubits 3..0); static-offset reads ----
#pragma unroll
        for (int m = 0; m < 16; ++m)
            v[m] = *(const float2*)(stb + baseC + (m << 11));
        apply_gate<0>(v, U[l][3]);
        apply_gate<1>(v, U[l][2]);
        apply_gate<2>(v, U[l][1]);
        apply_gate<3>(v, U[l][0]);

        if (l < NL - 1) {
            __syncthreads();   // bar2: all reads consumed before scatter overwrites
            // CNOT-ring fused scatter: amp i -> address of f^-1(i)
#pragma unroll
            for (int m = 0; m < 16; ++m)
                *(float2*)(stb + (baseS ^ scat_c(m))) = v[m];
            __syncthreads();   // bar3: next layer's pass A reads own slice
        }
    }

    // ---- layer-4: fuse CNOT perm + measurement from registers ----
    float z0 = 0.f, z1 = 0.f, z2 = 0.f, z3 = 0.f;
#pragma unroll
    for (int m = 0; m < 16; ++m) {
        const float pr = fmaf(v[m].x, v[m].x, v[m].y * v[m].y);
        const int h = meas_h(m) ^ hT;   // bits 11..8 of f^-1((m<<8)|t)
        z0 += (h & 8) ? -pr : pr;
        z1 += (h & 4) ? -pr : pr;
        z2 += (h & 2) ? -pr : pr;
        z3 += (h & 1) ? -pr : pr;
    }
#pragma unroll
    for (int off = 32; off > 0; off >>= 1) {
        z0 += __shfl_xor(z0, off);
        z1 += __shfl_xor(z1, off);
        z2 += __shfl_xor(z2, off);
        z3 += __shfl_xor(z3, off);
    }
    if ((tid & 63) == 0) {
        wz[w][0] = z0; wz[w][1] = z1; wz[w][2] = z2; wz[w][3] = z3;
    }
    __syncthreads();
    if (tid < 4) {
        const float z = wz[0][tid] + wz[1][tid] + wz[2][tid] + wz[3][tid];
        out[b * 4 + tid] = ow[tid] * z;
    }
}

extern "C" void kernel_launch(void* const* d_in, const int* in_sizes, int n_in,
                              void* d_out, int out_size, void* d_ws, size_t ws_size,
                              hipStream_t stream) {
    const float* x  = (const float*)d_in[0];
    const float* iw = (const float*)d_in[1];
    const float* th = (const float*)d_in[2];
    const float* ow = (const float*)d_in[3];
    float* out = (float*)d_out;
    const int batch = in_sizes[0] / NQ;
    hipLaunchKernelGGL(qnet_kernel, dim3(batch), dim3(TPB), 0, stream,
                       x, iw, th, ow, out);
}

// Round 6
// 50.340 us; speedup vs baseline: 1.0249x; 1.0231x over previous
//
#include <hip/hip_runtime.h>

#define NQ 12
#define NL 5
#define TPB 256

// ---------- compile-time address algebra (GF(2)-linear, R3-verified) ----------
__host__ __device__ constexpr int sfx12_(int x) {
    x ^= x >> 1; x ^= x >> 2; x ^= x >> 4; x ^= x >> 8;
    return x & 0xFFF;
}
__host__ __device__ constexpr int par_(int x) {
    int y = x; y ^= y >> 8; y ^= y >> 4; y ^= y >> 2; y ^= y >> 1;
    return y & 1;
}
// amp i lives at byte (G<<4)|((i&1)<<3), G = g ^ ((g>>3)&7), g = i>>1.  Linear in i.
__host__ __device__ constexpr int amp_addr(int i) {
    const int g = i >> 1;
    const int G = g ^ ((g >> 3) & 7);
    return (G << 4) | ((i & 1) << 3);
}
// CNOT ring: new[i]=old[f(i)], f(j)=j^(j>>1)^((j&1)*0xC00); f^-1(i)=sfx12(i)^(par(i)<<11).
__host__ __device__ constexpr int scat_c(int m) {          // scatter m-part address
    const int s = sfx12_(m << 8);
    return amp_addr(s ^ ((s & 1) << 11));
}
__host__ __device__ constexpr int bpat(int m) { return amp_addr(m << 4); }   // pass-B m-part
__host__ __device__ constexpr int meas_h(int m) {          // bits 11..8 of f^-1(m<<8)
    const int d = sfx12_(m << 8) ^ (par_(m) << 11);
    return (d >> 8) & 15;
}

// ---------- gate kernels ----------
__device__ __forceinline__ void gate_pair(float2 &a, float2 &c,
        const float2 u00, const float2 u01, const float2 u10, const float2 u11) {
    float2 n0, n1;
    n0.x = fmaf(u00.x, a.x, fmaf(-u00.y, a.y, fmaf(u01.x, c.x, -u01.y * c.y)));
    n0.y = fmaf(u00.x, a.y, fmaf( u00.y, a.x, fmaf(u01.x, c.y,  u01.y * c.x)));
    n1.x = fmaf(u10.x, a.x, fmaf(-u10.y, a.y, fmaf(u11.x, c.x, -u11.y * c.y)));
    n1.y = fmaf(u10.x, a.y, fmaf( u10.y, a.x, fmaf(u11.x, c.y,  u11.y * c.x)));
    a = n0; c = n1;
}
template <int K>
__device__ __forceinline__ void apply_gate(float2 (&v)[16], const float2* __restrict__ Uq) {
    const float2 u00 = Uq[0], u01 = Uq[1], u10 = Uq[2], u11 = Uq[3];
#pragma unroll
    for (int h = 0; h < 8; ++h) {
        const int m0 = ((h >> K) << (K + 1)) | (h & ((1 << K) - 1));
        gate_pair(v[m0], v[m0 | (1 << K)], u00, u01, u10, u11);
    }
}

extern "C" __global__ void __launch_bounds__(TPB)
qnet_kernel(const float* __restrict__ x, const float* __restrict__ iw,
            const float* __restrict__ th, const float* __restrict__ ow,
            float* __restrict__ out) {
    __shared__ float2 st[4096];                      // 32 KB state, swizzled
    __shared__ __align__(16) float2 U[NL][NQ][4];    // gate matrices
    __shared__ float wz[4][4];
    char* stb = (char*)st;

    const int b = blockIdx.x;
    const int tid = threadIdx.x;
    const int w = tid >> 6;

    // --- precompute all 60 gate matrices U = M(b,c) @ Rx(a) ---
    if (tid < NL * NQ) {
        const int l = tid / NQ, q = tid % NQ;
        const float xv = tanhf(x[b * NQ + q]);
        const float a = iw[l * NQ + q] * xv;
        const float bt = th[(l * NQ + q) * 2 + 0];
        const float ct = th[(l * NQ + q) * 2 + 1];
        float sa, ca; sincosf(0.5f * a, &sa, &ca);
        float sb, cb; sincosf(0.5f * bt, &sb, &cb);
        float sc, cc; sincosf(0.5f * ct, &sc, &cc);
        const float M00r = cc * cb, M00i = -sc * cb;
        const float M01r = -cc * sb, M01i = sc * sb;
        const float M10r = cc * sb, M10i = sc * sb;
        const float M11r = cc * cb, M11i = sc * cb;
        U[l][q][0] = make_float2(fmaf(M00r, ca,  sa * M01i), fmaf(M00i, ca, -sa * M01r));
        U[l][q][1] = make_float2(fmaf(ca, M01r,  sa * M00i), fmaf(ca, M01i, -sa * M00r));
        U[l][q][2] = make_float2(fmaf(M10r, ca,  sa * M11i), fmaf(M10i, ca, -sa * M11r));
        U[l][q][3] = make_float2(fmaf(ca, M11r,  sa * M10i), fmaf(ca, M11i, -sa * M10r));
    }

    // --- per-thread address bases (1 XOR w/ const per LDS access in the loop) ---
    const int baseA = amp_addr(tid << 4);                              // ^ (c<<4)
    const int baseB = amp_addr(((tid >> 4) << 8) | (tid & 15));        // ^ bpat(m)
    const int baseC = amp_addr(tid);                                   // + (m<<11)
    const int pt = __popc(tid) & 1;
    const int baseS = amp_addr(sfx12_(tid) ^ (pt << 11));              // ^ scat_c(m)
    const int hT = pt << 3;                                            // f^-1 t-part hi nibble

    __syncthreads();   // U visible

    float2 v[16];
    // Rolled layer loop: hot body ~12 KB, fits shared L1I (unrolled = ~68 KB, streams).
#pragma unroll 1
    for (int l = 0; l < NL; ++l) {
        // ---- pass A: amp bits 0-3 (qubits 11..8) ----
        if (l == 0) {
#pragma unroll
            for (int r = 0; r < 16; ++r) v[r] = make_float2(0.f, 0.f);
            if (tid == 0) v[0].x = 1.f;          // |0...0>
        } else {
#pragma unroll
            for (int c = 0; c < 8; ++c) {
                const float4 f = *(const float4*)(stb + (baseA ^ (c << 4)));
                v[2 * c]     = make_float2(f.x, f.y);
                v[2 * c + 1] = make_float2(f.z, f.w);
            }
        }
        apply_gate<0>(v, U[l][11]);
        apply_gate<1>(v, U[l][10]);
        apply_gate<2>(v, U[l][9]);
        apply_gate<3>(v, U[l][8]);
#pragma unroll
        for (int c = 0; c < 8; ++c)
            *(float4*)(stb + (baseA ^ (c << 4))) =
                make_float4(v[2 * c].x, v[2 * c].y, v[2 * c + 1].x, v[2 * c + 1].y);
        __syncthreads();

        // ---- pass B: amp bits 4-7 (qubits 7..4) ----
#pragma unroll
        for (int m = 0; m < 16; ++m)
            v[m] = *(const float2*)(stb + (baseB ^ bpat(m)));
        apply_gate<0>(v, U[l][7]);
        apply_gate<1>(v, U[l][6]);
        apply_gate<2>(v, U[l][5]);
        apply_gate<3>(v, U[l][4]);
#pragma unroll
        for (int m = 0; m < 16; ++m)
            *(float2*)(stb + (baseB ^ bpat(m))) = v[m];
        __syncthreads();

        // ---- pass C: amp bits 8-11 (qubits 3..0); static-offset reads ----
#pragma unroll
        for (int m = 0; m < 16; ++m)
            v[m] = *(const float2*)(stb + baseC + (m << 11));
        apply_gate<0>(v, U[l][3]);
        apply_gate<1>(v, U[l][2]);
        apply_gate<2>(v, U[l][1]);
        apply_gate<3>(v, U[l][0]);

        if (l != NL - 1) {
            __syncthreads();   // all pass-C reads consumed before scatter overwrites
            // CNOT-ring fused scatter: amp i -> address of f^-1(i)
#pragma unroll
            for (int m = 0; m < 16; ++m)
                *(float2*)(stb + (baseS ^ scat_c(m))) = v[m];
            __syncthreads();   // scatter visible to next layer's pass A
        }
    }

    // ---- layer-4: CNOT perm + measurement fused, straight from registers ----
    float z0 = 0.f, z1 = 0.f, z2 = 0.f, z3 = 0.f;
#pragma unroll
    for (int m = 0; m < 16; ++m) {
        const float pr = fmaf(v[m].x, v[m].x, v[m].y * v[m].y);
        const int h = meas_h(m) ^ hT;   // bits 11..8 of f^-1((m<<8)|tid)
        z0 += (h & 8) ? -pr : pr;
        z1 += (h & 4) ? -pr : pr;
        z2 += (h & 2) ? -pr : pr;
        z3 += (h & 1) ? -pr : pr;
    }
#pragma unroll
    for (int off = 32; off > 0; off >>= 1) {
        z0 += __shfl_xor(z0, off);
        z1 += __shfl_xor(z1, off);
        z2 += __shfl_xor(z2, off);
        z3 += __shfl_xor(z3, off);
    }
    if ((tid & 63) == 0) {
        wz[w][0] = z0; wz[w][1] = z1; wz[w][2] = z2; wz[w][3] = z3;
    }
    __syncthreads();
    if (tid < 4) {
        const float z = wz[0][tid] + wz[1][tid] + wz[2][tid] + wz[3][tid];
        out[b * 4 + tid] = ow[tid] * z;
    }
}

extern "C" void kernel_launch(void* const* d_in, const int* in_sizes, int n_in,
                              void* d_out, int out_size, void* d_ws, size_t ws_size,
                              hipStream_t stream) {
    const float* x  = (const float*)d_in[0];
    const float* iw = (const float*)d_in[1];
    const float* th = (const float*)d_in[2];
    const float* ow = (const float*)d_in[3];
    float* out = (float*)d_out;
    const int batch = in_sizes[0] / NQ;
    hipLaunchKernelGGL(qnet_kernel, dim3(batch), dim3(TPB), 0, stream,
                       x, iw, th, ow, out);
}